// Round 7
// baseline (496.630 us; speedup 1.0000x reference)
//
#include <hip/hip_runtime.h>
#include <hip/hip_fp16.h>

#define BB 4
#define CC 3
#define HH 384
#define WW 384
#define HW (HH * WW)
#define NP 13          // planes 0..11 = forward half-window aff, 12 = g = mask/sumz
#define NITER 20
#define PADF 2048      // guard floats around x buffers (max OOB reach is 779)
#define GUARDH 1024    // zeroed halves before each weight plane (bwd reads reach -772)
#define PSTRIDE (HW + GUARDH)

static constexpr float INV_Z2 = 1.0f / (0.15f * 0.15f);

// Half-window taps d=(dr,dc): dr>0 or (dr==0 && dc>0).
// plane idx: (0,1)->0 (0,2)->1 (1,-2..2)->2..6 (2,-2..2)->7..11.
// aff(p,p+d)==aff(p+d,p)  =>  backward contribution at p is A_d(p-d)*x(p-d).
// Column-OOB backward reads wrap linearly onto pixels whose stored forward
// aff is exactly 0 (prep zeroes 2D-OOB taps, since exp underflows after the
// +10 shift anyway); row-OOB backward reads land in the zeroed per-plane
// front guard. => iteration kernel is 100% branch-free.

// ---------------------------------------------------------------------------
__global__ __launch_bounds__(256) void zero_guards(__half* __restrict__ wgt)
{
    // one block per plane (52 planes), 256 threads x 4 halves = 1024 halves
    __half* g = wgt + (size_t)blockIdx.x * PSTRIDE + (size_t)threadIdx.x * 4;
    *(float2*)g = make_float2(0.f, 0.f);
}

// ---------------------------------------------------------------------------
__global__ __launch_bounds__(256) void prep_sym(
    const float* __restrict__ img, const float* __restrict__ feat,
    const float* __restrict__ mask, __half* __restrict__ wgt,
    float* __restrict__ x0)
{
    int gid = blockIdx.x * 256 + threadIdx.x;
    int p0 = gid * 2;
    if (p0 >= BB * HW) return;
    int b   = p0 / HW;
    int rem = p0 - b * HW;          // even
    int h   = rem / WW;
    int wc  = rem - h * WW;

    const float* imgb = img + (size_t)b * CC * HW;
    const size_t bHW = (size_t)b * HW;

    float2 f  = *(const float2*)(feat + bHW + rem);
    float2 mk = *(const float2*)(mask + bHW + rem);
    *(float2*)(x0 + bHW + rem) = make_float2(f.x * mk.x, f.y * mk.y);

    float v0[2], v1[2], v2[2];
#pragma unroll
    for (int s = 0; s < 2; ++s) {
        v0[s] = imgb[0 * HW + rem + s] + 10.f;
        v1[s] = imgb[1 * HW + rem + s] + 10.f;
        v2[s] = imgb[2 * HW + rem + s] + 10.f;
    }

    float a[12][2];
    float sz[2] = {1.f + 1e-10f, 1.f + 1e-10f};   // center aff = exp(0) = 1
#pragma unroll
    for (int dr = -2; dr <= 2; ++dr) {
#pragma unroll
        for (int dc = -2; dc <= 2; ++dc) {
            if (dr == 0 && dc == 0) continue;
            int rr = h + dr;
#pragma unroll
            for (int s = 0; s < 2; ++s) {
                int cc2 = wc + s + dc;
                float av = 0.f;
                if (rr >= 0 && rr < HH && cc2 >= 0 && cc2 < WW) {
                    int q = rr * WW + cc2;
                    float d0 = imgb[0 * HW + q] + 10.f - v0[s];
                    float d1 = imgb[1 * HW + q] + 10.f - v1[s];
                    float d2 = imgb[2 * HW + q] + 10.f - v2[s];
                    av = __expf(-(d0 * d0 + d1 * d1 + d2 * d2) * INV_Z2);
                }
                sz[s] += av;
                if (dr > 0 || (dr == 0 && dc > 0)) {
                    int idx = (dr == 0) ? (dc - 1) : (2 + (dr - 1) * 5 + (dc + 2));
                    a[idx][s] = av;
                }
            }
        }
    }
#pragma unroll
    for (int t = 0; t < 12; ++t)
        *(__half2*)(wgt + (size_t)(b * NP + t) * PSTRIDE + GUARDH + rem) =
            __floats2half2_rn(a[t][0], a[t][1]);
    *(__half2*)(wgt + (size_t)(b * NP + 12) * PSTRIDE + GUARDH + rem) =
        __floats2half2_rn(mk.x / sz[0], mk.y / sz[1]);
}

// ---------------------------------------------------------------------------
// weight fetch helpers, 8 px/thread (rem multiple of 8)
// ---------------------------------------------------------------------------
__device__ __forceinline__ void fwd_w8(const __half* __restrict__ plane,
                                       int rem, float w[8])
{
    float4 v = *(const float4*)(plane + rem);           // 16B aligned
    const __half2* h2 = (const __half2*)&v;
#pragma unroll
    for (int i = 0; i < 4; ++i) {
        float2 f = __half22float2(h2[i]);
        w[2 * i] = f.x; w[2 * i + 1] = f.y;
    }
}

// 8 halves starting at (misaligned) index q0; shift s = q0&3 is a
// compile-time constant at every call site (dc is an unrolled constant),
// so the branch and shifts fold away.
__device__ __forceinline__ void bwd_w8(const __half* __restrict__ plane,
                                       int q0, float w[8])
{
    const int s = q0 & 3;
    const __half* pa = plane + (q0 - s);                // 8B aligned
    union { float2 f[3]; unsigned u[6]; } U;
    U.f[0] = *(const float2*)pa;                        // halves 0..3
    U.f[1] = *(const float2*)(pa + 4);                  // halves 4..7
    U.f[2] = *(const float2*)(pa + 8);                  // halves 8..11
    unsigned e[4];
    const int sh = s >> 1;
    if (s & 1) {
        // halves starting at 2*sh+1: alignbit(hi,lo,16) = {hi,lo}>>16
#pragma unroll
        for (int i = 0; i < 4; ++i)
            e[i] = __builtin_amdgcn_alignbit(U.u[sh + i + 1], U.u[sh + i], 16);
    } else {
#pragma unroll
        for (int i = 0; i < 4; ++i)
            e[i] = U.u[sh + i];
    }
#pragma unroll
    for (int i = 0; i < 4; ++i) {
        float2 f = __half22float2(*(__half2*)&e[i]);
        w[2 * i] = f.x; w[2 * i + 1] = f.y;
    }
}

// 16 floats from p (16B aligned): xs[k] = p[k], covers offsets [-4, 12)
// relative to the row base when called with base rem+dr*WW-4.
__device__ __forceinline__ void loadx16(const float* __restrict__ p, float xs[16])
{
    float4 a0 = *(const float4*)p;
    float4 a1 = *(const float4*)(p + 4);
    float4 a2 = *(const float4*)(p + 8);
    float4 a3 = *(const float4*)(p + 12);
    xs[0]  = a0.x; xs[1]  = a0.y; xs[2]  = a0.z; xs[3]  = a0.w;
    xs[4]  = a1.x; xs[5]  = a1.y; xs[6]  = a1.z; xs[7]  = a1.w;
    xs[8]  = a2.x; xs[9]  = a2.y; xs[10] = a2.z; xs[11] = a2.w;
    xs[12] = a3.x; xs[13] = a3.y; xs[14] = a3.z; xs[15] = a3.w;
}

// ---------------------------------------------------------------------------
// Index convention: thread owns pixels p_j = rem+j, j in [0,8).
//   xs loaded from row base rem+dr*WW-4  =>  offset o maps to xs[o+4].
//   forward tap d=(dr,dc):  acc[j] += A_t[rem+j]            * xs[j+dc+4]
//   backward tap d=(dr,dc): acc[j] += A_t[rem-dr*WW-dc + j] * xs[j-dc+4]
//   (all indices j±dc+4 lie in [2,13] ⊂ [0,16))
// ---------------------------------------------------------------------------
__global__ __launch_bounds__(256) void iter_sym8(
    const __half* __restrict__ wgt, const float* __restrict__ xin,
    float* __restrict__ xout)
{
    int gid = blockIdx.x * 256 + threadIdx.x;
    int p0 = gid * 8;                       // grid sized exactly
    int b   = p0 / HW;
    int rem = p0 - b * HW;                  // multiple of 8
    const size_t bHW = (size_t)b * HW;

    const __half* wb = wgt + (size_t)b * NP * PSTRIDE + GUARDH;
    const float*  xb = xin + bHW;

    float acc[8] = {0, 0, 0, 0, 0, 0, 0, 0};
    float xs[16], w[8];

    // ---- x row h-2: backward taps of planes (2,dc) = 7..11 ----
    loadx16(xb + rem - 2 * WW - 4, xs);
#pragma unroll
    for (int dci = 0; dci < 5; ++dci) {
        const int dc = dci - 2;
        bwd_w8(wb + (size_t)(7 + dci) * PSTRIDE, rem - 2 * WW - dc, w);
#pragma unroll
        for (int j = 0; j < 8; ++j)
            acc[j] = fmaf(w[j], xs[j - dc + 4], acc[j]);
    }

    // ---- x row h-1: backward taps of planes (1,dc) = 2..6 ----
    loadx16(xb + rem - WW - 4, xs);
#pragma unroll
    for (int dci = 0; dci < 5; ++dci) {
        const int dc = dci - 2;
        bwd_w8(wb + (size_t)(2 + dci) * PSTRIDE, rem - WW - dc, w);
#pragma unroll
        for (int j = 0; j < 8; ++j)
            acc[j] = fmaf(w[j], xs[j - dc + 4], acc[j]);
    }

    // ---- x row h: center + fwd/bwd of planes (0,1),(0,2) ----
    loadx16(xb + rem - 4, xs);
#pragma unroll
    for (int j = 0; j < 8; ++j)            // center tap, weight exactly 1
        acc[j] += xs[j + 4];
#pragma unroll
    for (int t = 0; t < 2; ++t) {          // forward (0,dc)
        const int dc = t + 1;
        fwd_w8(wb + (size_t)t * PSTRIDE, rem, w);
#pragma unroll
        for (int j = 0; j < 8; ++j)
            acc[j] = fmaf(w[j], xs[j + dc + 4], acc[j]);
    }
#pragma unroll
    for (int t = 0; t < 2; ++t) {          // backward (0,dc)
        const int dc = t + 1;
        bwd_w8(wb + (size_t)t * PSTRIDE, rem - dc, w);
#pragma unroll
        for (int j = 0; j < 8; ++j)
            acc[j] = fmaf(w[j], xs[j - dc + 4], acc[j]);
    }

    // ---- x row h+1: forward taps of planes (1,dc) = 2..6 ----
    loadx16(xb + rem + WW - 4, xs);
#pragma unroll
    for (int dci = 0; dci < 5; ++dci) {
        const int dc = dci - 2;
        fwd_w8(wb + (size_t)(2 + dci) * PSTRIDE, rem, w);
#pragma unroll
        for (int j = 0; j < 8; ++j)
            acc[j] = fmaf(w[j], xs[j + dc + 4], acc[j]);
    }

    // ---- x row h+2: forward taps of planes (2,dc) = 7..11 ----
    loadx16(xb + rem + 2 * WW - 4, xs);
#pragma unroll
    for (int dci = 0; dci < 5; ++dci) {
        const int dc = dci - 2;
        fwd_w8(wb + (size_t)(7 + dci) * PSTRIDE, rem, w);
#pragma unroll
        for (int j = 0; j < 8; ++j)
            acc[j] = fmaf(w[j], xs[j + dc + 4], acc[j]);
    }

    // ---- normalizer g = mask/sumz, then store ----
    fwd_w8(wb + (size_t)12 * PSTRIDE, rem, w);
    float4 o0 = make_float4(acc[0] * w[0], acc[1] * w[1],
                            acc[2] * w[2], acc[3] * w[3]);
    float4 o1 = make_float4(acc[4] * w[4], acc[5] * w[5],
                            acc[6] * w[6], acc[7] * w[7]);
    *(float4*)(xout + bHW + rem)     = o0;
    *(float4*)(xout + bHW + rem + 4) = o1;
}

extern "C" void kernel_launch(void* const* d_in, const int* in_sizes, int n_in,
                              void* d_out, int out_size, void* d_ws, size_t ws_size,
                              hipStream_t stream)
{
    const float* img  = (const float*)d_in[0];
    const float* feat = (const float*)d_in[1];
    const float* mask = (const float*)d_in[2];
    float* out = (float*)d_out;

    // ws: [ wgt: 52 planes x (GUARDH+HW) halves (~15.4 MB) | PADF | xa | PADF | xb | PADF ]
    __half* wgt = (__half*)d_ws;
    size_t wbytes = (size_t)BB * NP * PSTRIDE * sizeof(__half);
    float* fbase = (float*)((char*)wgt + ((wbytes + 255) & ~(size_t)255));
    float* xa = fbase + PADF;
    float* xb = xa + (size_t)BB * HW + PADF;

    const int n = BB * HW;

    zero_guards<<<BB * NP, 256, 0, stream>>>(wgt);
    prep_sym<<<(n / 2 + 255) / 256, 256, 0, stream>>>(img, feat, mask, wgt, xa);

    const int iblocks = n / 8 / 256;   // 288, exact
    float* cur = xa;
    float* nxt = xb;
    for (int it = 0; it < NITER - 1; ++it) {
        iter_sym8<<<iblocks, 256, 0, stream>>>(wgt, cur, nxt);
        float* t = cur; cur = nxt; nxt = t;
    }
    iter_sym8<<<iblocks, 256, 0, stream>>>(wgt, cur, out);
}

// Round 8
// 242.197 us; speedup vs baseline: 2.0505x; 2.0505x over previous
//
#include <hip/hip_runtime.h>
#include <hip/hip_fp16.h>

#define BB 4
#define CC 3
#define HH 384
#define WW 384
#define HW (HH * WW)
#define K2 25
#define NITER 20
#define RSTRIP 6              // output rows per block (64 strips x 4 batches = 256 blocks)
#define YROWS (RSTRIP + 4)    // intermediate rows in LDS
#define YPITCH 392            // 384 + 4 pad each side
#define PADF 2048             // guard floats around x buffers (max OOB reach ~1544)

static constexpr float INV_Z2 = 1.0f / (0.15f * 0.15f);

// ---------------------------------------------------------------------------
// prep: 2 px/thread. Per-pixel 5x5 normalized affinity with mask(p) folded in
// (exact identity), fp16 planes wgt[b][t][pix]; x0 = feat*mask.
// OOB taps are exactly 0 (+10 shift -> exp underflows), so iteration kernels
// read x branch-free through padded guards / zero pads.
// ---------------------------------------------------------------------------
__global__ __launch_bounds__(256) void prep2(
    const float* __restrict__ img, const float* __restrict__ feat,
    const float* __restrict__ mask, __half* __restrict__ wgt,
    float* __restrict__ x0)
{
    int gid = blockIdx.x * 256 + threadIdx.x;
    int p0 = gid * 2;
    if (p0 >= BB * HW) return;
    int b   = p0 / HW;
    int rem = p0 - b * HW;          // even
    int h   = rem / WW;
    int wc  = rem - h * WW;

    const float* imgb = img + (size_t)b * CC * HW;
    const size_t bHW = (size_t)b * HW;

    float2 f  = *(const float2*)(feat + bHW + rem);
    float2 mk = *(const float2*)(mask + bHW + rem);
    *(float2*)(x0 + bHW + rem) = make_float2(f.x * mk.x, f.y * mk.y);

    float v0[2], v1[2], v2[2];
#pragma unroll
    for (int s = 0; s < 2; ++s) {
        v0[s] = imgb[0 * HW + rem + s] + 10.f;
        v1[s] = imgb[1 * HW + rem + s] + 10.f;
        v2[s] = imgb[2 * HW + rem + s] + 10.f;
    }

    float a[2][K2];
    float sz[2] = {1e-10f, 1e-10f};
#pragma unroll
    for (int t = 0; t < K2; ++t) {
        int dr = t / 5 - 2, dc = t % 5 - 2;
        int rr = h + dr;
#pragma unroll
        for (int s = 0; s < 2; ++s) {
            int cc2 = wc + s + dc;
            float av = 0.f;
            if (rr >= 0 && rr < HH && cc2 >= 0 && cc2 < WW) {
                int q = rr * WW + cc2;
                float d0 = imgb[0 * HW + q] + 10.f - v0[s];
                float d1 = imgb[1 * HW + q] + 10.f - v1[s];
                float d2 = imgb[2 * HW + q] + 10.f - v2[s];
                av = __expf(-(d0 * d0 + d1 * d1 + d2 * d2) * INV_Z2);
            }
            a[s][t] = av;
            sz[s] += av;
        }
    }
    float i0 = mk.x / sz[0], i1 = mk.y / sz[1];   // mask folded into weights
#pragma unroll
    for (int t = 0; t < K2; ++t) {
        __half2 hv = __floats2half2_rn(a[0][t] * i0, a[1][t] * i1);
        *(__half2*)(wgt + ((size_t)b * K2 + t) * HW + rem) = hv;
    }
}

// ---------------------------------------------------------------------------
// One quad (4 px) of one propagation iteration, x from GLOBAL.
// rem = r*WW + c0, c0 % 4 == 0. Branch-free; OOB x reads hit guard pads and
// meet exactly-zero weights.
// ---------------------------------------------------------------------------
__device__ __forceinline__ void quad_from_global(
    const __half* __restrict__ wb, const float* __restrict__ xb,
    int rem, float acc[4])
{
    acc[0] = acc[1] = acc[2] = acc[3] = 0.f;
#pragma unroll
    for (int dr = -2; dr <= 2; ++dr) {
        const float* p = xb + rem + dr * WW - 4;
        float xs[12];
        float4 a0 = *(const float4*)p;
        float4 a1 = *(const float4*)(p + 4);
        float4 a2 = *(const float4*)(p + 8);
        xs[0] = a0.x; xs[1] = a0.y; xs[2]  = a0.z; xs[3]  = a0.w;
        xs[4] = a1.x; xs[5] = a1.y; xs[6]  = a1.z; xs[7]  = a1.w;
        xs[8] = a2.x; xs[9] = a2.y; xs[10] = a2.z; xs[11] = a2.w;
#pragma unroll
        for (int dc = 0; dc < 5; ++dc) {
            const int t = (dr + 2) * 5 + dc;
            float2 wv2 = *(const float2*)(wb + (size_t)t * HW + rem);
            const __half2* hp = (const __half2*)&wv2;
            float2 w01 = __half22float2(hp[0]);
            float2 w23 = __half22float2(hp[1]);
            acc[0] = fmaf(w01.x, xs[dc + 2], acc[0]);
            acc[1] = fmaf(w01.y, xs[dc + 3], acc[1]);
            acc[2] = fmaf(w23.x, xs[dc + 4], acc[2]);
            acc[3] = fmaf(w23.y, xs[dc + 5], acc[3]);
        }
    }
}

// ---------------------------------------------------------------------------
// Fused 2 iterations. Block = batch b, rows [r0, r0+6).
// Stage 1: iter k on rows [r0-2, r0+8) -> LDS y (halo recomputed, consistent
// across blocks). Stage 2: iter k+1 on rows [r0, r0+6) from LDS -> global.
// ---------------------------------------------------------------------------
__global__ __launch_bounds__(256) void fuse2(
    const __half* __restrict__ wgt, const float* __restrict__ xin,
    float* __restrict__ xout)
{
    __shared__ float y[YROWS][YPITCH];

    const int wg = blockIdx.x;
    const int b  = wg >> 6;              // 64 strips per batch
    const int r0 = (wg & 63) * RSTRIP;
    const int tid = threadIdx.x;
    const size_t bHW = (size_t)b * HW;

    const __half* wb = wgt + (size_t)b * K2 * HW;
    const float*  xb = xin + bHW;

    // zero the 4-float pads on both sides of each LDS row (80 floats)
    if (tid < 2 * YROWS) {
        int rr = tid >> 1;
        int side = tid & 1;
        float* pz = &y[rr][side ? 388 : 0];
        pz[0] = pz[1] = pz[2] = pz[3] = 0.f;
    }

    // ---- stage 1: 10 rows x 96 quads = 960 quads ----
#pragma unroll
    for (int k = 0; k < 4; ++k) {
        int q = tid + k * 256;
        if (q < YROWS * 96) {
            int rl = q / 96;             // 0..9
            int c0 = (q - rl * 96) * 4;
            int r  = r0 - 2 + rl;
            float acc[4] = {0.f, 0.f, 0.f, 0.f};
            if (r >= 0 && r < HH)
                quad_from_global(wb, xb, r * WW + c0, acc);
            y[rl][c0 + 4] = acc[0];
            y[rl][c0 + 5] = acc[1];
            y[rl][c0 + 6] = acc[2];
            y[rl][c0 + 7] = acc[3];
        }
    }
    __syncthreads();

    // ---- stage 2: 6 rows x 96 quads = 576 quads, x from LDS ----
#pragma unroll
    for (int k = 0; k < 3; ++k) {
        int q = tid + k * 256;
        if (q < RSTRIP * 96) {
            int rl = q / 96;             // 0..5
            int c0 = (q - rl * 96) * 4;
            int r  = r0 + rl;
            int rem = r * WW + c0;
            int ly  = rl + 2;

            float acc[4] = {0.f, 0.f, 0.f, 0.f};
#pragma unroll
            for (int dr = -2; dr <= 2; ++dr) {
                const float* yp = &y[ly + dr][c0];   // covers cols c0-4 .. c0+7
                float xs[12];
                float4 a0 = *(const float4*)yp;
                float4 a1 = *(const float4*)(yp + 4);
                float4 a2 = *(const float4*)(yp + 8);
                xs[0] = a0.x; xs[1] = a0.y; xs[2]  = a0.z; xs[3]  = a0.w;
                xs[4] = a1.x; xs[5] = a1.y; xs[6]  = a1.z; xs[7]  = a1.w;
                xs[8] = a2.x; xs[9] = a2.y; xs[10] = a2.z; xs[11] = a2.w;
#pragma unroll
                for (int dc = 0; dc < 5; ++dc) {
                    const int t = (dr + 2) * 5 + dc;
                    float2 wv2 = *(const float2*)(wb + (size_t)t * HW + rem);
                    const __half2* hp = (const __half2*)&wv2;
                    float2 w01 = __half22float2(hp[0]);
                    float2 w23 = __half22float2(hp[1]);
                    acc[0] = fmaf(w01.x, xs[dc + 2], acc[0]);
                    acc[1] = fmaf(w01.y, xs[dc + 3], acc[1]);
                    acc[2] = fmaf(w23.x, xs[dc + 4], acc[2]);
                    acc[3] = fmaf(w23.y, xs[dc + 5], acc[3]);
                }
            }
            *(float4*)(xout + bHW + rem) =
                make_float4(acc[0], acc[1], acc[2], acc[3]);
        }
    }
}

extern "C" void kernel_launch(void* const* d_in, const int* in_sizes, int n_in,
                              void* d_out, int out_size, void* d_ws, size_t ws_size,
                              hipStream_t stream)
{
    const float* img  = (const float*)d_in[0];
    const float* feat = (const float*)d_in[1];
    const float* mask = (const float*)d_in[2];
    float* out = (float*)d_out;

    // ws: [ wgt: B*25*HW halves (~29.5 MB) | PADF | xa | PADF | xb | PADF ]
    __half* wgt = (__half*)d_ws;
    float* fbase = (float*)((char*)d_ws +
        (((size_t)BB * K2 * HW * sizeof(__half) + 255) & ~(size_t)255));
    float* xa = fbase + PADF;
    float* xb = xa + (size_t)BB * HW + PADF;

    const int n = BB * HW;
    prep2<<<(n / 2 + 255) / 256, 256, 0, stream>>>(img, feat, mask, wgt, xa);

    // 10 fused launches x 2 iterations
    float* cur = xa;
    float* nxt = xb;
    for (int it = 0; it < NITER / 2 - 1; ++it) {
        fuse2<<<256, 256, 0, stream>>>(wgt, cur, nxt);
        float* t = cur; cur = nxt; nxt = t;
    }
    fuse2<<<256, 256, 0, stream>>>(wgt, cur, out);
}